// Round 7
// baseline (316.995 us; speedup 1.0000x reference)
//
#include <hip/hip_runtime.h>
#include <math.h>

typedef unsigned short u16;
typedef unsigned int   u32;
typedef __attribute__((ext_vector_type(8))) __bf16 bf16x8;
typedef __attribute__((ext_vector_type(4))) float  f32x4;

#define BB 16
#define LL 2048
#define DD 512
#define NF 1025
#define TOPK 4

// ws layout (float-unit offsets), total ~136 MB
static const size_t OFF_XB  = 0;                         // bf16 x row-major [B*L][D]
static const size_t OFF_XTB = OFF_XB  + 8388608;         // bf16 x transposed [B][D][L]
static const size_t OFF_GTB = OFF_XTB + 8388608;         // bf16 G transposed [B][D][L]
static const size_t OFF_XC  = OFF_GTB + 8388608;         // bf16 combined x [B*L][D]
static const size_t OFF_BBM = OFF_XC  + 8388608;         // bf16 Bmat [1024][512]: 0..511=M, 512..1023=Wv
static const size_t OFF_S   = OFF_BBM + 262144;          // spectra [B][NF][2]
static const size_t OFF_W   = OFF_S   + (size_t)BB * NF * 2;
static const size_t OFF_I   = OFF_W   + BB * TOPK;

__device__ __forceinline__ u16 f2bf(float f) {
    u32 u = __float_as_uint(f);
    return (u16)((u + 0x7fffu + ((u >> 16) & 1u)) >> 16);
}
__device__ __forceinline__ float bf2f(u16 h) {
    return __uint_as_float(((u32)h) << 16);
}
__device__ __forceinline__ void gload16(const void* g, void* l) {
    __builtin_amdgcn_global_load_lds((const __attribute__((address_space(1))) void*)g,
                                     (__attribute__((address_space(3))) void*)l, 16, 0, 0);
}
__device__ __forceinline__ float2 cmul(float2 u, float2 v) {
    return make_float2(u.x * v.x - u.y * v.y, u.x * v.y + u.y * v.x);
}
__device__ __forceinline__ float2 cadd(float2 u, float2 v) { return make_float2(u.x + v.x, u.y + v.y); }
__device__ __forceinline__ float2 csub(float2 u, float2 v) { return make_float2(u.x - v.x, u.y - v.y); }

// Pair-granular padded index: pairs (i>>1) get 1 pad-pair per 8 pairs.
// Even i -> even phys -> every float4 (pair) access stays 16B aligned, and
// pairs (i, i+1) are always physically contiguous. Max PE(2047)=2301 < 2304.
__device__ __forceinline__ int PE(int i) { return i + ((i >> 4) << 1); }

// ---------------------------------------------------------------------------
// PAIRED radix-4 Stockham stage: thread does butterflies w0=2*tid and w0+1,
// which share jm (M>=2) -> one twiddle read + one T2/T3 per thread, and all
// LDS traffic is b128 (pairs). Math per butterfly identical to the verified
// R3 code. M=512 has jm==0 -> identity, specialized.
template<int M, int SGN>
__device__ __forceinline__ void radix4p(const float2* __restrict__ src,
                                        float2* __restrict__ dst,
                                        const float2* __restrict__ twl, int tid) {
    const int w0 = 2 * tid;
    const int k0 = w0 & (M - 1);     // even
    const int jm = w0 - k0;          // shared by w0 and w0+1
    const float4 A = *(const float4*)&src[PE(w0)];
    const float4 B = *(const float4*)&src[PE(w0 + 512)];
    const float4 C = *(const float4*)&src[PE(w0 + 1024)];
    const float4 D = *(const float4*)&src[PE(w0 + 1536)];
    const int o = 4 * jm + k0;       // even
    float2 y00, y10, y20, y30, y01, y11, y21, y31;
    {   // e = 0  (butterfly w0)
        float2 a = make_float2(A.x, A.y), b = make_float2(B.x, B.y);
        float2 c = make_float2(C.x, C.y), d = make_float2(D.x, D.y);
        float2 t0 = cadd(a, c), t1 = csub(a, c), t2 = cadd(b, d), bd = csub(b, d);
        float2 t3 = (SGN > 0) ? make_float2(bd.y, -bd.x) : make_float2(-bd.y, bd.x);
        y00 = cadd(t0, t2); y10 = cadd(t1, t3); y20 = csub(t0, t2); y30 = csub(t1, t3);
    }
    {   // e = 1  (butterfly w0+1)
        float2 a = make_float2(A.z, A.w), b = make_float2(B.z, B.w);
        float2 c = make_float2(C.z, C.w), d = make_float2(D.z, D.w);
        float2 t0 = cadd(a, c), t1 = csub(a, c), t2 = cadd(b, d), bd = csub(b, d);
        float2 t3 = (SGN > 0) ? make_float2(bd.y, -bd.x) : make_float2(-bd.y, bd.x);
        y01 = cadd(t0, t2); y11 = cadd(t1, t3); y21 = csub(t0, t2); y31 = csub(t1, t3);
    }
    if (M != 512) {
        float2 T1 = twl[jm];
        float2 T2 = cmul(T1, T1);
        float2 T3 = cmul(T1, T2);
        y10 = cmul(y10, T1); y11 = cmul(y11, T1);
        y20 = cmul(y20, T2); y21 = cmul(y21, T2);
        y30 = cmul(y30, T3); y31 = cmul(y31, T3);
    }
    *(float4*)&dst[PE(o)]         = make_float4(y00.x, y00.y, y01.x, y01.y);
    *(float4*)&dst[PE(o + M)]     = make_float4(y10.x, y10.y, y11.x, y11.y);
    *(float4*)&dst[PE(o + 2 * M)] = make_float4(y20.x, y20.y, y21.x, y21.y);
    *(float4*)&dst[PE(o + 3 * M)] = make_float4(y30.x, y30.y, y31.x, y31.y);
}

// 5 paired radix-4 stages (input = m=2 Stockham state from the fused radix-2).
// b1 -> ... -> result in b2. Caller barriers before entry.
template<int SGN>
__device__ __forceinline__ void fft_r4_chain(float2* __restrict__ b1, float2* __restrict__ b2,
                                             const float2* __restrict__ twl, int tid) {
    radix4p<2,   SGN>(b1, b2, twl, tid); __syncthreads();
    radix4p<8,   SGN>(b2, b1, twl, tid); __syncthreads();
    radix4p<32,  SGN>(b1, b2, twl, tid); __syncthreads();
    radix4p<128, SGN>(b2, b1, twl, tid); __syncthreads();
    radix4p<512, SGN>(b1, b2, twl, tid); __syncthreads();
}

// ---------------------------------------------------------------------------
// Merged prologue. Branch order = dispatch order:
//   bid 0..63      : gemm1 M = Wq^T*Wk       (latency-heavy, starts FIRST)
//   bid 64..319    : cast Wv + zero S
//   bid 320..2367  : transpose x -> XTB only (32d x 256t tiles, 512B-chunk writes)
//   bid 2368..10559: streaming cast x -> XB  (linear, 16B/lane contiguous)
__global__ __launch_bounds__(256) void k_pre(const float* __restrict__ x,
                                             const float* __restrict__ Wq,
                                             const float* __restrict__ Wk,
                                             const float* __restrict__ Wv,
                                             u16* __restrict__ xb,
                                             u16* __restrict__ xtb,
                                             u16* __restrict__ Bm,
                                             float* __restrict__ S) {
    __shared__ char sh[16768];
    int bid = blockIdx.x;
    int tid = threadIdx.x;
    if (bid < 64) {
        // ---- gemm1 branch: M = Wq^T * Wk -> bf16 rows 0..511 of Bmat
        int g = bid;
        float (*As)[68] = (float(*)[68])sh;
        float (*Bs)[68] = (float(*)[68])(sh + 4352);
        int tx = tid & 15, ty = tid >> 4;
        int m0 = (g & 7) * 64, n0 = (g >> 3) * 64;
        float acc[4][4] = {};
        for (int k0 = 0; k0 < DD; k0 += 16) {
#pragma unroll
            for (int r = 0; r < 4; r++) {
                As[ty][tx + 16 * r] = Wq[(size_t)(k0 + ty) * DD + m0 + tx + 16 * r];
                Bs[ty][tx + 16 * r] = Wk[(size_t)(k0 + ty) * DD + n0 + tx + 16 * r];
            }
            __syncthreads();
#pragma unroll
            for (int k = 0; k < 16; k++) {
                float4 a4 = *(const float4*)&As[k][ty * 4];
                float4 b4 = *(const float4*)&Bs[k][tx * 4];
                float a[4] = {a4.x, a4.y, a4.z, a4.w};
                float b[4] = {b4.x, b4.y, b4.z, b4.w};
#pragma unroll
                for (int i = 0; i < 4; i++)
#pragma unroll
                    for (int j = 0; j < 4; j++) acc[i][j] += a[i] * b[j];
            }
            __syncthreads();
        }
#pragma unroll
        for (int i = 0; i < 4; i++) {
            uint2 o;
            o.x = (u32)f2bf(acc[i][0]) | ((u32)f2bf(acc[i][1]) << 16);
            o.y = (u32)f2bf(acc[i][2]) | ((u32)f2bf(acc[i][3]) << 16);
            *(uint2*)&Bm[(size_t)(m0 + ty * 4 + i) * DD + n0 + tx * 4] = o;
        }
    } else if (bid < 320) {
        // ---- misc branch: cast Wv (rows 512..1023 of Bmat), zero S
        int g = bid - 64;                    // 0..255
        int i4 = g * 256 + tid;              // float4 index over 512*512
        float4 w = ((const float4*)Wv)[i4];
        ushort4 o;
        o.x = f2bf(w.x); o.y = f2bf(w.y); o.z = f2bf(w.z); o.w = f2bf(w.w);
        ((ushort4*)(Bm + DD * DD))[i4] = o;
        if (i4 < 8200)                       // 32800 floats = 8200 float4
            ((float4*)S)[i4] = make_float4(0.f, 0.f, 0.f, 0.f);
    } else if (bid < 2368) {
        // ---- transpose branch: x fp32 -> XTB bf16 [b][d][t], 32d x 256t tile.
        int tb = bid - 320;                  // 0..2047
        int bx = tb & 15;                    // d-tile (16 x 32)
        int by = (tb >> 4) & 7;              // t-tile (8 x 256)
        int bz = tb >> 7;                    // batch
        u32* tile32 = (u32*)sh;              // [32][131] u32 = 16768 B
        int tx = tid & 7, ty = tid >> 3;     // tx: d-quad, ty: 0..31
        int d0 = bx * 32, t0 = by * 256;
        const float* ip = x + ((size_t)bz * LL + t0) * DD + d0 + tx * 4;
        float4 va[4], vb[4];
#pragma unroll
        for (int ii = 0; ii < 4; ii++) {
            int h = ty + 32 * ii;
            va[ii] = *(const float4*)&ip[(size_t)(2 * h) * DD];
            vb[ii] = *(const float4*)&ip[(size_t)(2 * h + 1) * DD];
        }
#pragma unroll
        for (int ii = 0; ii < 4; ii++) {
            int h = ty + 32 * ii;
            u32 a0 = f2bf(va[ii].x), a1 = f2bf(va[ii].y), a2 = f2bf(va[ii].z), a3 = f2bf(va[ii].w);
            u32 b0 = f2bf(vb[ii].x), b1 = f2bf(vb[ii].y), b2 = f2bf(vb[ii].z), b3 = f2bf(vb[ii].w);
            tile32[(4 * tx + 0) * 131 + h] = a0 | (b0 << 16);
            tile32[(4 * tx + 1) * 131 + h] = a1 | (b1 << 16);
            tile32[(4 * tx + 2) * 131 + h] = a2 | (b2 << 16);
            tile32[(4 * tx + 3) * 131 + h] = a3 | (b3 << 16);
        }
        __syncthreads();
        u16* xtp = xtb + ((size_t)bz * DD + d0) * LL + t0;
#pragma unroll
        for (int u = 0; u < 4; u++) {
            int idx = u * 256 + tid;         // 0..1023
            int dr = idx >> 5;               // d row 0..31
            int ch = idx & 31;               // 16 B chunk within 512 B row
            const u32* rp = tile32 + dr * 131 + ch * 4;
            uint4 o = make_uint4(rp[0], rp[1], rp[2], rp[3]);
            *(uint4*)&xtp[(size_t)dr * LL + ch * 8] = o;
        }
    } else {
        // ---- streaming cast branch: x fp32 -> XB bf16, linear walk.
        size_t g = (size_t)(bid - 2368) * 256 + tid;   // uint4 index over XB
        const float4* x4 = (const float4*)x;
        float4 a = x4[2 * g], b = x4[2 * g + 1];
        uint4 o;
        o.x = (u32)f2bf(a.x) | ((u32)f2bf(a.y) << 16);
        o.y = (u32)f2bf(a.z) | ((u32)f2bf(a.w) << 16);
        o.z = (u32)f2bf(b.x) | ((u32)f2bf(b.y) << 16);
        o.w = (u32)f2bf(b.z) | ((u32)f2bf(b.w) << 16);
        ((uint4*)xb)[g] = o;
    }
}

// ---------------------------------------------------------------------------
// G = XB * M^T (bf16 MFMA), written transposed bf16 GTB[b][d][t].
__global__ __launch_bounds__(256, 2) void k_gemm2(const u16* __restrict__ Ab,
                                                  const u16* __restrict__ Bm,
                                                  u16* __restrict__ GTB) {
    __shared__ u16 smem[16384];
    u16* As = smem;
    u16* Bs = smem + 8192;
    int t = threadIdx.x;
    int wave = t >> 6, lane = t & 63;
    int l15 = lane & 15, l4 = lane >> 4;
    int qr = wave & 1, qc = wave >> 1;
    int m0 = blockIdx.x * 128, n0 = blockIdx.y * 128;

    f32x4 acc[4][4];
#pragma unroll
    for (int i = 0; i < 4; i++)
#pragma unroll
        for (int j = 0; j < 4; j++) acc[i][j] = (f32x4){0.f, 0.f, 0.f, 0.f};

    const u16* Ag = Ab + (size_t)m0 * DD;
    const u16* Bg = Bm + (size_t)n0 * DD;
    int a_base = (qr * 64 + l15) * 64 + l4 * 8;
    int b_base = (qc * 64 + l15) * 64 + l4 * 8;

    for (int k0 = 0; k0 < DD; k0 += 64) {
#pragma unroll
        for (int n = 0; n < 4; n++) {
            int c = wave * 256 + n * 64 + lane;
            int row = c >> 3, col = (c & 7) * 8;
            gload16(Ag + (size_t)row * DD + k0 + col, (char*)As + (size_t)(wave * 256 + n * 64) * 16);
            gload16(Bg + (size_t)row * DD + k0 + col, (char*)Bs + (size_t)(wave * 256 + n * 64) * 16);
        }
        __syncthreads();
#pragma unroll
        for (int kk = 0; kk < 64; kk += 32) {
            bf16x8 af[4], bq[4];
#pragma unroll
            for (int i = 0; i < 4; i++) af[i] = *(const bf16x8*)(As + a_base + i * 1024 + kk);
#pragma unroll
            for (int j = 0; j < 4; j++) bq[j] = *(const bf16x8*)(Bs + b_base + j * 1024 + kk);
#pragma unroll
            for (int i = 0; i < 4; i++)
#pragma unroll
                for (int j = 0; j < 4; j++)
                    acc[i][j] = __builtin_amdgcn_mfma_f32_16x16x32_bf16(af[i], bq[j], acc[i][j], 0, 0, 0);
        }
        __syncthreads();
    }

    // Epilogue: transposed bf16 write via swizzled LDS staging
    float4* tb4 = (float4*)smem;
    int bidx = m0 >> 11;
    int tbase = m0 & 2047;
#pragma unroll
    for (int p = 0; p < 2; p++) {
        __syncthreads();
        if (qc == p) {
#pragma unroll
            for (int j = 0; j < 4; j++) {
                int nloc = j * 16 + l15;
#pragma unroll
                for (int i = 0; i < 4; i++) {
                    int tq = qr * 16 + i * 4 + l4;
                    tb4[nloc * 32 + (tq ^ (nloc & 31))] = *(float4*)&acc[i][j];
                }
            }
        }
        __syncthreads();
#pragma unroll
        for (int u = 0; u < 8; u++) {
            int idx4 = u * 256 + t;
            int nloc = idx4 >> 5, c4 = idx4 & 31;
            float4 v = tb4[nloc * 32 + (c4 ^ (nloc & 31))];
            uint2 o;
            o.x = (u32)f2bf(v.x) | ((u32)f2bf(v.y) << 16);
            o.y = (u32)f2bf(v.z) | ((u32)f2bf(v.w) << 16);
            *(uint2*)&GTB[((size_t)bidx * DD + n0 + p * 64 + nloc) * LL + tbase + c4 * 4] = o;
        }
    }
}

// ---------------------------------------------------------------------------
// out = XC * Wv^T + bv (bf16 MFMA), row-major fp32 into d_out.
__global__ __launch_bounds__(256, 2) void k_gemm3(const u16* __restrict__ Ab,
                                                  const u16* __restrict__ Bm,
                                                  const float* __restrict__ bv,
                                                  float* __restrict__ out) {
    __shared__ u16 smem[16384];
    u16* As = smem;
    u16* Bs = smem + 8192;
    int t = threadIdx.x;
    int wave = t >> 6, lane = t & 63;
    int l15 = lane & 15, l4 = lane >> 4;
    int qr = wave & 1, qc = wave >> 1;
    int m0 = blockIdx.x * 128, n0 = blockIdx.y * 128;

    f32x4 acc[4][4];
#pragma unroll
    for (int i = 0; i < 4; i++)
#pragma unroll
        for (int j = 0; j < 4; j++) acc[i][j] = (f32x4){0.f, 0.f, 0.f, 0.f};

    const u16* Ag = Ab + (size_t)m0 * DD;
    const u16* Bg = Bm + (size_t)DD * DD + (size_t)n0 * DD;
    int a_base = (qr * 64 + l15) * 64 + l4 * 8;
    int b_base = (qc * 64 + l15) * 64 + l4 * 8;

    for (int k0 = 0; k0 < DD; k0 += 64) {
#pragma unroll
        for (int n = 0; n < 4; n++) {
            int c = wave * 256 + n * 64 + lane;
            int row = c >> 3, col = (c & 7) * 8;
            gload16(Ag + (size_t)row * DD + k0 + col, (char*)As + (size_t)(wave * 256 + n * 64) * 16);
            gload16(Bg + (size_t)row * DD + k0 + col, (char*)Bs + (size_t)(wave * 256 + n * 64) * 16);
        }
        __syncthreads();
#pragma unroll
        for (int kk = 0; kk < 64; kk += 32) {
            bf16x8 af[4], bq[4];
#pragma unroll
            for (int i = 0; i < 4; i++) af[i] = *(const bf16x8*)(As + a_base + i * 1024 + kk);
#pragma unroll
            for (int j = 0; j < 4; j++) bq[j] = *(const bf16x8*)(Bs + b_base + j * 1024 + kk);
#pragma unroll
            for (int i = 0; i < 4; i++)
#pragma unroll
                for (int j = 0; j < 4; j++)
                    acc[i][j] = __builtin_amdgcn_mfma_f32_16x16x32_bf16(af[i], bq[j], acc[i][j], 0, 0, 0);
        }
        __syncthreads();
    }

    float*  tb  = (float*)smem;
    float4* tb4 = (float4*)smem;
#pragma unroll
    for (int p = 0; p < 2; p++) {
        __syncthreads();
        if (qr == p) {
#pragma unroll
            for (int j = 0; j < 4; j++) {
                int nloc = qc * 64 + j * 16 + l15;
#pragma unroll
                for (int i = 0; i < 4; i++) {
#pragma unroll
                    for (int r = 0; r < 4; r++) {
                        int mloc = i * 16 + l4 * 4 + r;
                        int nc = ((nloc >> 2) ^ (mloc & 31)) << 2;
                        tb[mloc * 128 + nc + (nloc & 3)] = acc[i][j][r];
                    }
                }
            }
        }
        __syncthreads();
#pragma unroll
        for (int u = 0; u < 8; u++) {
            int idx4 = u * 256 + t;
            int mloc = idx4 >> 5, c4 = idx4 & 31;
            float4 v = tb4[mloc * 32 + (c4 ^ (mloc & 31))];
            float4 bias = *(const float4*)&bv[n0 + c4 * 4];
            v.x += bias.x; v.y += bias.y; v.z += bias.z; v.w += bias.w;
            *(float4*)&out[(size_t)(m0 + p * 64 + mloc) * DD + n0 + c4 * 4] = v;
        }
    }
}

// ---------------------------------------------------------------------------
// Per (b, 8-channel group): packed FFT of z = x_d + i*G_d. Radix-2 fused into
// the load phase; 5 PAIRED radix-4 stages (all-b128 LDS traffic); Hermitian
// split accumulated in registers. Pair-padded LDS PE() keeps b128 aligned.
// LDS = 40960 B -> 4 blocks/CU; grid 1024 -> full residency.
__global__ __launch_bounds__(256) void k_fft(const u16* __restrict__ XTB,
                                             const u16* __restrict__ GTB,
                                             float* __restrict__ S) {
    __shared__ __align__(16) float2 lds[5120];   // b1[2304] | b2[2304] | twl[512] = 40960 B
    float2* b1  = lds;
    float2* b2  = lds + 2304;
    float2* twl = lds + 4608;
    int tid = threadIdx.x;
    int grp = blockIdx.x;    // 0..63
    int b = blockIdx.y;

    // 512-entry forward twiddle table (covers all radix-4 stage jm values)
    for (int j = tid; j < 512; j += 256) {
        float sn, cs;
        sincosf(-6.283185307179586f / 2048.0f * (float)j, &sn, &cs);
        twl[j] = make_float2(cs, sn);
    }
    // radix-2 twiddles for j = 4t..4t+3 (full 0..1023 range) in registers
    float2 tw2a, tw2b, tw2c, tw2d;
    {
        float sn, cs;
        sincosf(-6.283185307179586f / 2048.0f * (float)(4 * tid + 0), &sn, &cs); tw2a = make_float2(cs, sn);
        sincosf(-6.283185307179586f / 2048.0f * (float)(4 * tid + 1), &sn, &cs); tw2b = make_float2(cs, sn);
        sincosf(-6.283185307179586f / 2048.0f * (float)(4 * tid + 2), &sn, &cs); tw2c = make_float2(cs, sn);
        sincosf(-6.283185307179586f / 2048.0f * (float)(4 * tid + 3), &sn, &cs); tw2d = make_float2(cs, sn);
    }
    __syncthreads();

    float2 sr[4];
#pragma unroll
    for (int r = 0; r < 4; r++) sr[r] = make_float2(0.f, 0.f);
    float s1024 = 0.f;

    for (int c = 0; c < 8; c++) {
        int d = grp * 8 + c;
        const u16* xp = XTB + ((size_t)b * DD + d) * LL;
        const u16* gp = GTB + ((size_t)b * DD + d) * LL;
        // fused load + radix-2: thread t handles j = 4t..4t+3 paired with +1024.
        // Writes b1 elements 8t..8t+7 (phys-contiguous under PE, 16B aligned).
        int j0 = 4 * tid;
        uint2 xl = *(const uint2*)&xp[j0];
        uint2 xh = *(const uint2*)&xp[j0 + 1024];
        uint2 gl = *(const uint2*)&gp[j0];
        uint2 gh = *(const uint2*)&gp[j0 + 1024];
        float2* wp = &b1[PE(8 * tid)];
        {
            float2 a0 = make_float2(bf2f((u16)xl.x), bf2f((u16)gl.x));
            float2 c0 = make_float2(bf2f((u16)xh.x), bf2f((u16)gh.x));
            wp[0] = cadd(a0, c0);
            wp[1] = cmul(csub(a0, c0), tw2a);
            float2 a1 = make_float2(bf2f((u16)(xl.x >> 16)), bf2f((u16)(gl.x >> 16)));
            float2 c1 = make_float2(bf2f((u16)(xh.x >> 16)), bf2f((u16)(gh.x >> 16)));
            wp[2] = cadd(a1, c1);
            wp[3] = cmul(csub(a1, c1), tw2b);
            float2 a2 = make_float2(bf2f((u16)xl.y), bf2f((u16)gl.y));
            float2 c2 = make_float2(bf2f((u16)xh.y), bf2f((u16)gh.y));
            wp[4] = cadd(a2, c2);
            wp[5] = cmul(csub(a2, c2), tw2c);
            float2 a3 = make_float2(bf2f((u16)(xl.y >> 16)), bf2f((u16)(gl.y >> 16)));
            float2 c3 = make_float2(bf2f((u16)(xh.y >> 16)), bf2f((u16)(gh.y >> 16)));
            wp[6] = cadd(a3, c3);
            wp[7] = cmul(csub(a3, c3), tw2d);
        }
        __syncthreads();
        fft_r4_chain<1>(b1, b2, twl, tid);      // result in b2
        // Hermitian split + accumulate S += Xf * conj(Gf)  (registers)
        // Thread covers f = 2*tid + e + 512*h, h=0..1, e=0..1 -> sr[2h+e].
#pragma unroll
        for (int h = 0; h < 2; h++) {
            int f = 2 * tid + 512 * h;
            float4 pp = *(const float4*)&b2[PE(f)];
            float2 q0 = b2[PE((2048 - f) & 2047)];
            float2 q1 = b2[PE(2047 - f)];
            {   // e = 0
                float ar = 0.5f * (pp.x + q0.x), ai = 0.5f * (pp.y - q0.y);
                float dr = pp.x - q0.x, di = pp.y + q0.y;
                float gr = 0.5f * di, gi = -0.5f * dr;
                sr[2 * h].x += ar * gr + ai * gi;
                sr[2 * h].y += ai * gr - ar * gi;
            }
            {   // e = 1
                float ar = 0.5f * (pp.z + q1.x), ai = 0.5f * (pp.w - q1.y);
                float dr = pp.z - q1.x, di = pp.w + q1.y;
                float gr = 0.5f * di, gi = -0.5f * dr;
                sr[2 * h + 1].x += ar * gr + ai * gi;
                sr[2 * h + 1].y += ai * gr - ar * gi;
            }
        }
        if (tid == 0) {
            float2 p = b2[PE(1024)];
            s1024 += p.x * p.y;
        }
        // next load writes b1 (safe: last b1 reader barriered inside chain);
        // herm reads of b2 complete before next chain's first b2 write (which
        // is after the post-r2 __syncthreads).
    }
    float* Sg = S + (size_t)b * NF * 2;
#pragma unroll
    for (int u = 0; u < 4; u++) {
        int f = 2 * tid + (u & 1) + 512 * (u >> 1);
        atomicAdd(&Sg[2 * f], sr[u].x);
        atomicAdd(&Sg[2 * f + 1], sr[u].y);
    }
    if (tid == 0) {
        atomicAdd(&Sg[2048], s1024);
    }
}

// ---------------------------------------------------------------------------
// Per batch: inverse FFT (fused-r2 load of Hermitian-extended spectrum) ->
// mean_corr, top-4, softmax.
__global__ __launch_bounds__(256) void k_topk(const float* __restrict__ S,
                                              float* __restrict__ wts,
                                              int* __restrict__ idxs) {
    __shared__ __align__(16) float2 lds[5120];
    float2* b1  = lds;
    float2* b2  = lds + 2304;
    float2* twl = lds + 4608;
    __shared__ float cv[2048];
    __shared__ float rv[256];
    __shared__ int ri[256];
    __shared__ float topv[TOPK];
    __shared__ int topi[TOPK];
    int tid = threadIdx.x;
    int b = blockIdx.x;
    const float* Sg = S + (size_t)b * NF * 2;

    // 512-entry inverse twiddle table
    for (int j = tid; j < 512; j += 256) {
        float sn, cs;
        sincosf(6.283185307179586f / 2048.0f * (float)j, &sn, &cs);
        twl[j] = make_float2(cs, sn);
    }
    __syncthreads();

    // fused Hermitian-extension load + radix-2 -> b1 (register twiddles)
#pragma unroll
    for (int h = 0; h < 2; h++) {
#pragma unroll
        for (int e = 0; e < 2; e++) {
            int j = 2 * tid + 512 * h + e;
            float sn, cs;
            sincosf(6.283185307179586f / 2048.0f * (float)j, &sn, &cs);   // inverse sign
            float2 T = make_float2(cs, sn);
            float2 zl = make_float2(Sg[2 * j], Sg[2 * j + 1]);            // j <= 1023
            int fh = j + 1024;
            int ms = 2048 - fh;                                           // mirror for fh>1024
            float2 zh = (fh == 1024) ? make_float2(Sg[2048], Sg[2049])
                                     : make_float2(Sg[2 * ms], -Sg[2 * ms + 1]);
            float2 u = cadd(zl, zh);
            float2 v = cmul(csub(zl, zh), T);
            *(float4*)&b1[PE(2 * j)] = make_float4(u.x, u.y, v.x, v.y);
        }
    }
    __syncthreads();
    fft_r4_chain<-1>(b1, b2, twl, tid);   // result in b2
    const float scale = 1.0f / ((float)LL * (float)DD);
    for (int f = tid; f < 2048; f += 256) cv[f] = b2[PE(f)].x * scale;
    __syncthreads();
    for (int r = 0; r < TOPK; r++) {
        float best = -3.0e38f;
        int bi = 0x7fffffff;
        for (int f = tid; f < 2048; f += 256) {
            bool taken = false;
            for (int q = 0; q < r; q++) taken |= (topi[q] == f);
            float v = cv[f];
            if (!taken && (v > best || (v == best && f < bi))) { best = v; bi = f; }
        }
        rv[tid] = best; ri[tid] = bi;
        __syncthreads();
        for (int s = 128; s > 0; s >>= 1) {
            if (tid < s) {
                float v2 = rv[tid + s]; int i2 = ri[tid + s];
                if (v2 > rv[tid] || (v2 == rv[tid] && i2 < ri[tid])) { rv[tid] = v2; ri[tid] = i2; }
            }
            __syncthreads();
        }
        if (tid == 0) { topv[r] = rv[0]; topi[r] = ri[0]; }
        __syncthreads();
    }
    if (tid == 0) {
        float mx = topv[0];
        float e[TOPK], sum = 0.f;
        for (int k = 0; k < TOPK; k++) { e[k] = expf(topv[k] - mx); sum += e[k]; }
        for (int k = 0; k < TOPK; k++) {
            wts[b * TOPK + k] = e[k] / sum;
            idxs[b * TOPK + k] = topi[k];
        }
    }
}

// ---------------------------------------------------------------------------
// XC[b,l,:] = round_bf16( sum_k w_k * XB[b,(l-idx_k)&2047,:] )
__global__ __launch_bounds__(128) void k_combine(const u16* __restrict__ XB,
                                                 const float* __restrict__ wts,
                                                 const int* __restrict__ idxs,
                                                 u16* __restrict__ XC) {
    int l = blockIdx.x, b = blockIdx.y;
    int t = threadIdx.x;
    const ushort4* Xb = (const ushort4*)(XB + (size_t)b * LL * DD);
    float4 acc = make_float4(0.f, 0.f, 0.f, 0.f);
#pragma unroll
    for (int k = 0; k < TOPK; k++) {
        float w = wts[b * TOPK + k];
        int r = (l - idxs[b * TOPK + k]) & (LL - 1);
        ushort4 v = Xb[(size_t)r * 128 + t];
        acc.x += w * bf2f(v.x); acc.y += w * bf2f(v.y);
        acc.z += w * bf2f(v.z); acc.w += w * bf2f(v.w);
    }
    ushort4 o;
    o.x = f2bf(acc.x); o.y = f2bf(acc.y); o.z = f2bf(acc.z); o.w = f2bf(acc.w);
    ((ushort4*)(XC + (size_t)b * LL * DD))[(size_t)l * 128 + t] = o;
}

// ---------------------------------------------------------------------------
extern "C" void kernel_launch(void* const* d_in, const int* in_sizes, int n_in,
                              void* d_out, int out_size, void* d_ws, size_t ws_size,
                              hipStream_t stream) {
    const float* x  = (const float*)d_in[0];
    const float* Wq = (const float*)d_in[1];
    const float* Wk = (const float*)d_in[3];
    const float* Wv = (const float*)d_in[5];
    const float* bv = (const float*)d_in[6];
    // bq, bk provably cancel (tau-independent shift; top-k & softmax shift-invariant)
    (void)in_sizes; (void)n_in; (void)out_size; (void)ws_size;

    float* ws  = (float*)d_ws;
    u16*   XB  = (u16*)(ws + OFF_XB);
    u16*   XTB = (u16*)(ws + OFF_XTB);
    u16*   GTB = (u16*)(ws + OFF_GTB);
    u16*   XC  = (u16*)(ws + OFF_XC);
    u16*   BM  = (u16*)(ws + OFF_BBM);
    float* S   = ws + OFF_S;
    float* wts = ws + OFF_W;
    int*   idx = (int*)(ws + OFF_I);
    float* out = (float*)d_out;

    k_pre<<<10560, 256, 0, stream>>>(x, Wq, Wk, Wv, XB, XTB, BM, S);
    k_gemm2<<<dim3((BB * LL) / 128, DD / 128), 256, 0, stream>>>(XB, BM, GTB);
    k_fft<<<dim3(64, BB), 256, 0, stream>>>(XTB, GTB, S);
    k_topk<<<BB, 256, 0, stream>>>(S, wts, idx);
    k_combine<<<dim3(LL, BB), 128, 0, stream>>>(XB, wts, idx, XC);
    k_gemm3<<<dim3((BB * LL) / 128, DD / 128), 256, 0, stream>>>(XC, BM, bv, out);
}

// Round 8
// 305.324 us; speedup vs baseline: 1.0382x; 1.0382x over previous
//
#include <hip/hip_runtime.h>
#include <math.h>

typedef unsigned short u16;
typedef unsigned int   u32;
typedef __attribute__((ext_vector_type(8))) __bf16 bf16x8;
typedef __attribute__((ext_vector_type(4))) float  f32x4;

#define BB 16
#define LL 2048
#define DD 512
#define NF 1025
#define TOPK 4

// ws layout (float-unit offsets), total ~136 MB
static const size_t OFF_XB  = 0;                         // bf16 x row-major [B*L][D]
static const size_t OFF_XTB = OFF_XB  + 8388608;         // bf16 x transposed [B][D][L]
static const size_t OFF_GTB = OFF_XTB + 8388608;         // bf16 G transposed [B][D][L]
static const size_t OFF_XC  = OFF_GTB + 8388608;         // bf16 combined x [B*L][D]
static const size_t OFF_BBM = OFF_XC  + 8388608;         // bf16 Bmat [1024][512]: 0..511=M, 512..1023=Wv
static const size_t OFF_S   = OFF_BBM + 262144;          // spectra [B][NF][2]
static const size_t OFF_W   = OFF_S   + (size_t)BB * NF * 2;
static const size_t OFF_I   = OFF_W   + BB * TOPK;

__device__ __forceinline__ u16 f2bf(float f) {
    u32 u = __float_as_uint(f);
    return (u16)((u + 0x7fffu + ((u >> 16) & 1u)) >> 16);
}
__device__ __forceinline__ float bf2f(u16 h) {
    return __uint_as_float(((u32)h) << 16);
}
__device__ __forceinline__ void gload16(const void* g, void* l) {
    __builtin_amdgcn_global_load_lds((const __attribute__((address_space(1))) void*)g,
                                     (__attribute__((address_space(3))) void*)l, 16, 0, 0);
}
__device__ __forceinline__ float2 cmul(float2 u, float2 v) {
    return make_float2(u.x * v.x - u.y * v.y, u.x * v.y + u.y * v.x);
}
__device__ __forceinline__ float2 cadd(float2 u, float2 v) { return make_float2(u.x + v.x, u.y + v.y); }
__device__ __forceinline__ float2 csub(float2 u, float2 v) { return make_float2(u.x - v.x, u.y - v.y); }

// Bank-conflict-reducing padded index (1 pad per 8 float2). All Stockham
// access patterns land at <=4 lanes/bank-pair for b64 ops (free).
__device__ __forceinline__ int P(int i) { return i + (i >> 3); }

// ---------------------------------------------------------------------------
// Radix-4 Stockham stage (R4/R5-verified math), NT = threads in block.
// NT=512 -> one butterfly/thread (k_fft, max occupancy); NT=256 -> two
// (k_topk). Twiddles from the 512-entry LDS table (jm <= 511 always).
// M=512 has jm==0 -> identity, specialized.
template<int M, int SGN, int NT>
__device__ __forceinline__ void radix4(const float2* __restrict__ src,
                                       float2* __restrict__ dst,
                                       const float2* __restrict__ twl, int tid) {
#pragma unroll
    for (int r = 0; r < 512 / NT; r++) {
        int w = tid + NT * r;
        int k = w & (M - 1);
        int jm = w - k;
        float2 a = src[P(w)], b = src[P(w + 512)], c = src[P(w + 1024)], d = src[P(w + 1536)];
        float2 t0 = cadd(a, c), t1 = csub(a, c), t2 = cadd(b, d), bd = csub(b, d);
        float2 t3 = (SGN > 0) ? make_float2(bd.y, -bd.x)
                              : make_float2(-bd.y, bd.x);
        int o = 4 * jm + k;
        if (M == 512) {
            dst[P(o)]         = cadd(t0, t2);
            dst[P(o + M)]     = cadd(t1, t3);
            dst[P(o + 2 * M)] = csub(t0, t2);
            dst[P(o + 3 * M)] = csub(t1, t3);
        } else {
            float2 T1 = twl[jm];
            float2 T2 = cmul(T1, T1);
            float2 T3 = cmul(T1, T2);
            dst[P(o)]         = cadd(t0, t2);
            dst[P(o + M)]     = cmul(cadd(t1, t3), T1);
            dst[P(o + 2 * M)] = cmul(csub(t0, t2), T2);
            dst[P(o + 3 * M)] = cmul(csub(t1, t3), T3);
        }
    }
}

// 5 radix-4 stages (input = m=2 Stockham state from the fused radix-2).
// b1 -> ... -> result in b2. Caller barriers before entry.
template<int SGN, int NT>
__device__ __forceinline__ void fft_r4_chain(float2* __restrict__ b1, float2* __restrict__ b2,
                                             const float2* __restrict__ twl, int tid) {
    radix4<2,   SGN, NT>(b1, b2, twl, tid); __syncthreads();
    radix4<8,   SGN, NT>(b2, b1, twl, tid); __syncthreads();
    radix4<32,  SGN, NT>(b1, b2, twl, tid); __syncthreads();
    radix4<128, SGN, NT>(b2, b1, twl, tid); __syncthreads();
    radix4<512, SGN, NT>(b1, b2, twl, tid); __syncthreads();
}

// ---------------------------------------------------------------------------
// Merged prologue. Branch order = dispatch order:
//   bid 0..63      : gemm1 M = Wq^T*Wk       (latency-heavy, starts FIRST)
//   bid 64..319    : cast Wv + zero S
//   bid 320..2367  : transpose x -> XTB only (32d x 256t tiles, 512B-chunk writes)
//   bid 2368..10559: streaming cast x -> XB  (linear, 16B/lane contiguous)
__global__ __launch_bounds__(256) void k_pre(const float* __restrict__ x,
                                             const float* __restrict__ Wq,
                                             const float* __restrict__ Wk,
                                             const float* __restrict__ Wv,
                                             u16* __restrict__ xb,
                                             u16* __restrict__ xtb,
                                             u16* __restrict__ Bm,
                                             float* __restrict__ S) {
    __shared__ char sh[16768];
    int bid = blockIdx.x;
    int tid = threadIdx.x;
    if (bid < 64) {
        // ---- gemm1 branch: M = Wq^T * Wk -> bf16 rows 0..511 of Bmat
        int g = bid;
        float (*As)[68] = (float(*)[68])sh;
        float (*Bs)[68] = (float(*)[68])(sh + 4352);
        int tx = tid & 15, ty = tid >> 4;
        int m0 = (g & 7) * 64, n0 = (g >> 3) * 64;
        float acc[4][4] = {};
        for (int k0 = 0; k0 < DD; k0 += 16) {
#pragma unroll
            for (int r = 0; r < 4; r++) {
                As[ty][tx + 16 * r] = Wq[(size_t)(k0 + ty) * DD + m0 + tx + 16 * r];
                Bs[ty][tx + 16 * r] = Wk[(size_t)(k0 + ty) * DD + n0 + tx + 16 * r];
            }
            __syncthreads();
#pragma unroll
            for (int k = 0; k < 16; k++) {
                float4 a4 = *(const float4*)&As[k][ty * 4];
                float4 b4 = *(const float4*)&Bs[k][tx * 4];
                float a[4] = {a4.x, a4.y, a4.z, a4.w};
                float b[4] = {b4.x, b4.y, b4.z, b4.w};
#pragma unroll
                for (int i = 0; i < 4; i++)
#pragma unroll
                    for (int j = 0; j < 4; j++) acc[i][j] += a[i] * b[j];
            }
            __syncthreads();
        }
#pragma unroll
        for (int i = 0; i < 4; i++) {
            uint2 o;
            o.x = (u32)f2bf(acc[i][0]) | ((u32)f2bf(acc[i][1]) << 16);
            o.y = (u32)f2bf(acc[i][2]) | ((u32)f2bf(acc[i][3]) << 16);
            *(uint2*)&Bm[(size_t)(m0 + ty * 4 + i) * DD + n0 + tx * 4] = o;
        }
    } else if (bid < 320) {
        // ---- misc branch: cast Wv (rows 512..1023 of Bmat), zero S
        int g = bid - 64;                    // 0..255
        int i4 = g * 256 + tid;              // float4 index over 512*512
        float4 w = ((const float4*)Wv)[i4];
        ushort4 o;
        o.x = f2bf(w.x); o.y = f2bf(w.y); o.z = f2bf(w.z); o.w = f2bf(w.w);
        ((ushort4*)(Bm + DD * DD))[i4] = o;
        if (i4 < 8200)                       // 32800 floats = 8200 float4
            ((float4*)S)[i4] = make_float4(0.f, 0.f, 0.f, 0.f);
    } else if (bid < 2368) {
        // ---- transpose branch: x fp32 -> XTB bf16 [b][d][t], 32d x 256t tile.
        int tb = bid - 320;                  // 0..2047
        int bx = tb & 15;                    // d-tile (16 x 32)
        int by = (tb >> 4) & 7;              // t-tile (8 x 256)
        int bz = tb >> 7;                    // batch
        u32* tile32 = (u32*)sh;              // [32][131] u32 = 16768 B
        int tx = tid & 7, ty = tid >> 3;     // tx: d-quad, ty: 0..31
        int d0 = bx * 32, t0 = by * 256;
        const float* ip = x + ((size_t)bz * LL + t0) * DD + d0 + tx * 4;
        float4 va[4], vb[4];
#pragma unroll
        for (int ii = 0; ii < 4; ii++) {
            int h = ty + 32 * ii;
            va[ii] = *(const float4*)&ip[(size_t)(2 * h) * DD];
            vb[ii] = *(const float4*)&ip[(size_t)(2 * h + 1) * DD];
        }
#pragma unroll
        for (int ii = 0; ii < 4; ii++) {
            int h = ty + 32 * ii;
            u32 a0 = f2bf(va[ii].x), a1 = f2bf(va[ii].y), a2 = f2bf(va[ii].z), a3 = f2bf(va[ii].w);
            u32 b0 = f2bf(vb[ii].x), b1 = f2bf(vb[ii].y), b2 = f2bf(vb[ii].z), b3 = f2bf(vb[ii].w);
            tile32[(4 * tx + 0) * 131 + h] = a0 | (b0 << 16);
            tile32[(4 * tx + 1) * 131 + h] = a1 | (b1 << 16);
            tile32[(4 * tx + 2) * 131 + h] = a2 | (b2 << 16);
            tile32[(4 * tx + 3) * 131 + h] = a3 | (b3 << 16);
        }
        __syncthreads();
        u16* xtp = xtb + ((size_t)bz * DD + d0) * LL + t0;
#pragma unroll
        for (int u = 0; u < 4; u++) {
            int idx = u * 256 + tid;         // 0..1023
            int dr = idx >> 5;               // d row 0..31
            int ch = idx & 31;               // 16 B chunk within 512 B row
            const u32* rp = tile32 + dr * 131 + ch * 4;
            uint4 o = make_uint4(rp[0], rp[1], rp[2], rp[3]);
            *(uint4*)&xtp[(size_t)dr * LL + ch * 8] = o;
        }
    } else {
        // ---- streaming cast branch: x fp32 -> XB bf16, linear walk.
        size_t g = (size_t)(bid - 2368) * 256 + tid;   // uint4 index over XB
        const float4* x4 = (const float4*)x;
        float4 a = x4[2 * g], b = x4[2 * g + 1];
        uint4 o;
        o.x = (u32)f2bf(a.x) | ((u32)f2bf(a.y) << 16);
        o.y = (u32)f2bf(a.z) | ((u32)f2bf(a.w) << 16);
        o.z = (u32)f2bf(b.x) | ((u32)f2bf(b.y) << 16);
        o.w = (u32)f2bf(b.z) | ((u32)f2bf(b.w) << 16);
        ((uint4*)xb)[g] = o;
    }
}

// ---------------------------------------------------------------------------
// G = XB * M^T (bf16 MFMA), written transposed bf16 GTB[b][d][t].
__global__ __launch_bounds__(256, 2) void k_gemm2(const u16* __restrict__ Ab,
                                                  const u16* __restrict__ Bm,
                                                  u16* __restrict__ GTB) {
    __shared__ u16 smem[16384];
    u16* As = smem;
    u16* Bs = smem + 8192;
    int t = threadIdx.x;
    int wave = t >> 6, lane = t & 63;
    int l15 = lane & 15, l4 = lane >> 4;
    int qr = wave & 1, qc = wave >> 1;
    int m0 = blockIdx.x * 128, n0 = blockIdx.y * 128;

    f32x4 acc[4][4];
#pragma unroll
    for (int i = 0; i < 4; i++)
#pragma unroll
        for (int j = 0; j < 4; j++) acc[i][j] = (f32x4){0.f, 0.f, 0.f, 0.f};

    const u16* Ag = Ab + (size_t)m0 * DD;
    const u16* Bg = Bm + (size_t)n0 * DD;
    int a_base = (qr * 64 + l15) * 64 + l4 * 8;
    int b_base = (qc * 64 + l15) * 64 + l4 * 8;

    for (int k0 = 0; k0 < DD; k0 += 64) {
#pragma unroll
        for (int n = 0; n < 4; n++) {
            int c = wave * 256 + n * 64 + lane;
            int row = c >> 3, col = (c & 7) * 8;
            gload16(Ag + (size_t)row * DD + k0 + col, (char*)As + (size_t)(wave * 256 + n * 64) * 16);
            gload16(Bg + (size_t)row * DD + k0 + col, (char*)Bs + (size_t)(wave * 256 + n * 64) * 16);
        }
        __syncthreads();
#pragma unroll
        for (int kk = 0; kk < 64; kk += 32) {
            bf16x8 af[4], bq[4];
#pragma unroll
            for (int i = 0; i < 4; i++) af[i] = *(const bf16x8*)(As + a_base + i * 1024 + kk);
#pragma unroll
            for (int j = 0; j < 4; j++) bq[j] = *(const bf16x8*)(Bs + b_base + j * 1024 + kk);
#pragma unroll
            for (int i = 0; i < 4; i++)
#pragma unroll
                for (int j = 0; j < 4; j++)
                    acc[i][j] = __builtin_amdgcn_mfma_f32_16x16x32_bf16(af[i], bq[j], acc[i][j], 0, 0, 0);
        }
        __syncthreads();
    }

    // Epilogue: transposed bf16 write via swizzled LDS staging
    float4* tb4 = (float4*)smem;
    int bidx = m0 >> 11;
    int tbase = m0 & 2047;
#pragma unroll
    for (int p = 0; p < 2; p++) {
        __syncthreads();
        if (qc == p) {
#pragma unroll
            for (int j = 0; j < 4; j++) {
                int nloc = j * 16 + l15;
#pragma unroll
                for (int i = 0; i < 4; i++) {
                    int tq = qr * 16 + i * 4 + l4;
                    tb4[nloc * 32 + (tq ^ (nloc & 31))] = *(float4*)&acc[i][j];
                }
            }
        }
        __syncthreads();
#pragma unroll
        for (int u = 0; u < 8; u++) {
            int idx4 = u * 256 + t;
            int nloc = idx4 >> 5, c4 = idx4 & 31;
            float4 v = tb4[nloc * 32 + (c4 ^ (nloc & 31))];
            uint2 o;
            o.x = (u32)f2bf(v.x) | ((u32)f2bf(v.y) << 16);
            o.y = (u32)f2bf(v.z) | ((u32)f2bf(v.w) << 16);
            *(uint2*)&GTB[((size_t)bidx * DD + n0 + p * 64 + nloc) * LL + tbase + c4 * 4] = o;
        }
    }
}

// ---------------------------------------------------------------------------
// out = XC * Wv^T + bv (bf16 MFMA), row-major fp32 into d_out.
__global__ __launch_bounds__(256, 2) void k_gemm3(const u16* __restrict__ Ab,
                                                  const u16* __restrict__ Bm,
                                                  const float* __restrict__ bv,
                                                  float* __restrict__ out) {
    __shared__ u16 smem[16384];
    u16* As = smem;
    u16* Bs = smem + 8192;
    int t = threadIdx.x;
    int wave = t >> 6, lane = t & 63;
    int l15 = lane & 15, l4 = lane >> 4;
    int qr = wave & 1, qc = wave >> 1;
    int m0 = blockIdx.x * 128, n0 = blockIdx.y * 128;

    f32x4 acc[4][4];
#pragma unroll
    for (int i = 0; i < 4; i++)
#pragma unroll
        for (int j = 0; j < 4; j++) acc[i][j] = (f32x4){0.f, 0.f, 0.f, 0.f};

    const u16* Ag = Ab + (size_t)m0 * DD;
    const u16* Bg = Bm + (size_t)DD * DD + (size_t)n0 * DD;
    int a_base = (qr * 64 + l15) * 64 + l4 * 8;
    int b_base = (qc * 64 + l15) * 64 + l4 * 8;

    for (int k0 = 0; k0 < DD; k0 += 64) {
#pragma unroll
        for (int n = 0; n < 4; n++) {
            int c = wave * 256 + n * 64 + lane;
            int row = c >> 3, col = (c & 7) * 8;
            gload16(Ag + (size_t)row * DD + k0 + col, (char*)As + (size_t)(wave * 256 + n * 64) * 16);
            gload16(Bg + (size_t)row * DD + k0 + col, (char*)Bs + (size_t)(wave * 256 + n * 64) * 16);
        }
        __syncthreads();
#pragma unroll
        for (int kk = 0; kk < 64; kk += 32) {
            bf16x8 af[4], bq[4];
#pragma unroll
            for (int i = 0; i < 4; i++) af[i] = *(const bf16x8*)(As + a_base + i * 1024 + kk);
#pragma unroll
            for (int j = 0; j < 4; j++) bq[j] = *(const bf16x8*)(Bs + b_base + j * 1024 + kk);
#pragma unroll
            for (int i = 0; i < 4; i++)
#pragma unroll
                for (int j = 0; j < 4; j++)
                    acc[i][j] = __builtin_amdgcn_mfma_f32_16x16x32_bf16(af[i], bq[j], acc[i][j], 0, 0, 0);
        }
        __syncthreads();
    }

    float*  tb  = (float*)smem;
    float4* tb4 = (float4*)smem;
#pragma unroll
    for (int p = 0; p < 2; p++) {
        __syncthreads();
        if (qr == p) {
#pragma unroll
            for (int j = 0; j < 4; j++) {
                int nloc = qc * 64 + j * 16 + l15;
#pragma unroll
                for (int i = 0; i < 4; i++) {
#pragma unroll
                    for (int r = 0; r < 4; r++) {
                        int mloc = i * 16 + l4 * 4 + r;
                        int nc = ((nloc >> 2) ^ (mloc & 31)) << 2;
                        tb[mloc * 128 + nc + (nloc & 3)] = acc[i][j][r];
                    }
                }
            }
        }
        __syncthreads();
#pragma unroll
        for (int u = 0; u < 8; u++) {
            int idx4 = u * 256 + t;
            int mloc = idx4 >> 5, c4 = idx4 & 31;
            float4 v = tb4[mloc * 32 + (c4 ^ (mloc & 31))];
            float4 bias = *(const float4*)&bv[n0 + c4 * 4];
            v.x += bias.x; v.y += bias.y; v.z += bias.z; v.w += bias.w;
            *(float4*)&out[(size_t)(m0 + p * 64 + mloc) * DD + n0 + c4 * 4] = v;
        }
    }
}

// ---------------------------------------------------------------------------
// Per (b, 8-channel group): packed FFT of z = x_d + i*G_d. 512 THREADS: one
// butterfly/thread/stage -> 8 waves/block, 4 blocks/CU = 32 waves/CU (2x the
// 256-thread version) to cover LDS latency. Radix-2 fused into the load;
// 5 radix-4 stages (LDS twiddle table, P-pad); Hermitian split in registers.
// LDS = 40944 B; grid 1024 -> full residency.
__global__ __launch_bounds__(512, 8) void k_fft(const u16* __restrict__ XTB,
                                                const u16* __restrict__ GTB,
                                                float* __restrict__ S) {
    __shared__ float2 lds[5118];      // b1[2303] | b2[2303] | twl[512] = 40944 B
    float2* b1  = lds;
    float2* b2  = lds + 2303;
    float2* twl = lds + 4606;
    int tid = threadIdx.x;            // 0..511
    int grp = blockIdx.x;             // 0..63
    int b = blockIdx.y;

    // 512-entry forward twiddle table (covers all radix-4 stage jm values)
    if (tid < 512) {
        float sn, cs;
        sincosf(-6.283185307179586f / 2048.0f * (float)tid, &sn, &cs);
        twl[tid] = make_float2(cs, sn);
    }
    // radix-2 twiddles for j = 2t, 2t+1 in registers
    float2 tw2a, tw2b;
    {
        float sn, cs;
        sincosf(-6.283185307179586f / 2048.0f * (float)(2 * tid + 0), &sn, &cs); tw2a = make_float2(cs, sn);
        sincosf(-6.283185307179586f / 2048.0f * (float)(2 * tid + 1), &sn, &cs); tw2b = make_float2(cs, sn);
    }
    __syncthreads();

    float2 sr[2];
    sr[0] = make_float2(0.f, 0.f);
    sr[1] = make_float2(0.f, 0.f);
    float s1024 = 0.f;

    for (int c = 0; c < 8; c++) {
        int d = grp * 8 + c;
        const u16* xp = XTB + ((size_t)b * DD + d) * LL;
        const u16* gp = GTB + ((size_t)b * DD + d) * LL;
        // fused load + radix-2: thread t handles j = 2t, 2t+1 paired with +1024.
        // Writes b1 elements 4t..4t+3 (contiguous under P: no pad crossing).
        int j0 = 2 * tid;
        u32 xl = *(const u32*)&xp[j0];
        u32 xh = *(const u32*)&xp[j0 + 1024];
        u32 gl = *(const u32*)&gp[j0];
        u32 gh = *(const u32*)&gp[j0 + 1024];
        float2* wp = &b1[P(4 * tid)];
        {
            float2 a0 = make_float2(bf2f((u16)xl), bf2f((u16)gl));
            float2 c0 = make_float2(bf2f((u16)xh), bf2f((u16)gh));
            wp[0] = cadd(a0, c0);
            wp[1] = cmul(csub(a0, c0), tw2a);
            float2 a1 = make_float2(bf2f((u16)(xl >> 16)), bf2f((u16)(gl >> 16)));
            float2 c1 = make_float2(bf2f((u16)(xh >> 16)), bf2f((u16)(gh >> 16)));
            wp[2] = cadd(a1, c1);
            wp[3] = cmul(csub(a1, c1), tw2b);
        }
        __syncthreads();
        fft_r4_chain<1, 512>(b1, b2, twl, tid);      // result in b2
        // Hermitian split + accumulate S += Xf * conj(Gf)  (registers)
#pragma unroll
        for (int h = 0; h < 2; h++) {
            int f = tid + 512 * h;
            float2 p = b2[P(f)];
            float2 q = b2[P((2048 - f) & 2047)];
            float ar = 0.5f * (p.x + q.x), ai = 0.5f * (p.y - q.y);
            float dr = p.x - q.x, di = p.y + q.y;
            float gr = 0.5f * di, gi = -0.5f * dr;
            sr[h].x += ar * gr + ai * gi;
            sr[h].y += ai * gr - ar * gi;
        }
        if (tid == 0) {
            float2 p = b2[P(1024)];
            s1024 += p.x * p.y;
        }
        // next load writes b1 (safe: last b1 reader barriered inside chain);
        // herm reads of b2 complete before next chain's first b2 write (which
        // is after the post-r2 __syncthreads).
    }
    float* Sg = S + (size_t)b * NF * 2;
#pragma unroll
    for (int h = 0; h < 2; h++) {
        int f = tid + 512 * h;
        atomicAdd(&Sg[2 * f], sr[h].x);
        atomicAdd(&Sg[2 * f + 1], sr[h].y);
    }
    if (tid == 0) {
        atomicAdd(&Sg[2048], s1024);
    }
}

// ---------------------------------------------------------------------------
// Per batch: inverse FFT (fused-r2 load of Hermitian-extended spectrum) ->
// mean_corr, top-4, softmax. 256 threads (NT=256 chain), R4-verified.
__global__ __launch_bounds__(256) void k_topk(const float* __restrict__ S,
                                              float* __restrict__ wts,
                                              int* __restrict__ idxs) {
    __shared__ float2 lds[5118];
    float2* b1  = lds;
    float2* b2  = lds + 2303;
    float2* twl = lds + 4606;
    __shared__ float cv[2048];
    __shared__ float rv[256];
    __shared__ int ri[256];
    __shared__ float topv[TOPK];
    __shared__ int topi[TOPK];
    int tid = threadIdx.x;
    int b = blockIdx.x;
    const float* Sg = S + (size_t)b * NF * 2;

    // 512-entry inverse twiddle table
    for (int j = tid; j < 512; j += 256) {
        float sn, cs;
        sincosf(6.283185307179586f / 2048.0f * (float)j, &sn, &cs);
        twl[j] = make_float2(cs, sn);
    }
    __syncthreads();

    // fused Hermitian-extension load + radix-2 -> b1 (register twiddles)
#pragma unroll
    for (int h = 0; h < 2; h++) {
#pragma unroll
        for (int e = 0; e < 2; e++) {
            int j = 2 * tid + 512 * h + e;
            float sn, cs;
            sincosf(6.283185307179586f / 2048.0f * (float)j, &sn, &cs);   // inverse sign
            float2 T = make_float2(cs, sn);
            float2 zl = make_float2(Sg[2 * j], Sg[2 * j + 1]);            // j <= 1023
            int fh = j + 1024;
            int ms = 2048 - fh;                                           // mirror for fh>1024
            float2 zh = (fh == 1024) ? make_float2(Sg[2048], Sg[2049])
                                     : make_float2(Sg[2 * ms], -Sg[2 * ms + 1]);
            b1[P(2 * j)]     = cadd(zl, zh);
            b1[P(2 * j + 1)] = cmul(csub(zl, zh), T);
        }
    }
    __syncthreads();
    fft_r4_chain<-1, 256>(b1, b2, twl, tid);   // result in b2
    const float scale = 1.0f / ((float)LL * (float)DD);
    for (int f = tid; f < 2048; f += 256) cv[f] = b2[P(f)].x * scale;
    __syncthreads();
    for (int r = 0; r < TOPK; r++) {
        float best = -3.0e38f;
        int bi = 0x7fffffff;
        for (int f = tid; f < 2048; f += 256) {
            bool taken = false;
            for (int q = 0; q < r; q++) taken |= (topi[q] == f);
            float v = cv[f];
            if (!taken && (v > best || (v == best && f < bi))) { best = v; bi = f; }
        }
        rv[tid] = best; ri[tid] = bi;
        __syncthreads();
        for (int s = 128; s > 0; s >>= 1) {
            if (tid < s) {
                float v2 = rv[tid + s]; int i2 = ri[tid + s];
                if (v2 > rv[tid] || (v2 == rv[tid] && i2 < ri[tid])) { rv[tid] = v2; ri[tid] = i2; }
            }
            __syncthreads();
        }
        if (tid == 0) { topv[r] = rv[0]; topi[r] = ri[0]; }
        __syncthreads();
    }
    if (tid == 0) {
        float mx = topv[0];
        float e[TOPK], sum = 0.f;
        for (int k = 0; k < TOPK; k++) { e[k] = expf(topv[k] - mx); sum += e[k]; }
        for (int k = 0; k < TOPK; k++) {
            wts[b * TOPK + k] = e[k] / sum;
            idxs[b * TOPK + k] = topi[k];
        }
    }
}

// ---------------------------------------------------------------------------
// XC[b,l,:] = round_bf16( sum_k w_k * XB[b,(l-idx_k)&2047,:] )
__global__ __launch_bounds__(128) void k_combine(const u16* __restrict__ XB,
                                                 const float* __restrict__ wts,
                                                 const int* __restrict__ idxs,
                                                 u16* __restrict__ XC) {
    int l = blockIdx.x, b = blockIdx.y;
    int t = threadIdx.x;
    const ushort4* Xb = (const ushort4*)(XB + (size_t)b * LL * DD);
    float4 acc = make_float4(0.f, 0.f, 0.f, 0.f);
#pragma unroll
    for (int k = 0; k < TOPK; k++) {
        float w = wts[b * TOPK + k];
        int r = (l - idxs[b * TOPK + k]) & (LL - 1);
        ushort4 v = Xb[(size_t)r * 128 + t];
        acc.x += w * bf2f(v.x); acc.y += w * bf2f(v.y);
        acc.z += w * bf2f(v.z); acc.w += w * bf2f(v.w);
    }
    ushort4 o;
    o.x = f2bf(acc.x); o.y = f2bf(acc.y); o.z = f2bf(acc.z); o.w = f2bf(acc.w);
    ((ushort4*)(XC + (size_t)b * LL * DD))[(size_t)l * 128 + t] = o;
}

// ---------------------------------------------------------------------------
extern "C" void kernel_launch(void* const* d_in, const int* in_sizes, int n_in,
                              void* d_out, int out_size, void* d_ws, size_t ws_size,
                              hipStream_t stream) {
    const float* x  = (const float*)d_in[0];
    const float* Wq = (const float*)d_in[1];
    const float* Wk = (const float*)d_in[3];
    const float* Wv = (const float*)d_in[5];
    const float* bv = (const float*)d_in[6];
    // bq, bk provably cancel (tau-independent shift; top-k & softmax shift-invariant)
    (void)in_sizes; (void)n_in; (void)out_size; (void)ws_size;

    float* ws  = (float*)d_ws;
    u16*   XB  = (u16*)(ws + OFF_XB);
    u16*   XTB = (u16*)(ws + OFF_XTB);
    u16*   GTB = (u16*)(ws + OFF_GTB);
    u16*   XC  = (u16*)(ws + OFF_XC);
    u16*   BM  = (u16*)(ws + OFF_BBM);
    float* S   = ws + OFF_S;
    float* wts = ws + OFF_W;
    int*   idx = (int*)(ws + OFF_I);
    float* out = (float*)d_out;

    k_pre<<<10560, 256, 0, stream>>>(x, Wq, Wk, Wv, XB, XTB, BM, S);
    k_gemm2<<<dim3((BB * LL) / 128, DD / 128), 256, 0, stream>>>(XB, BM, GTB);
    k_fft<<<dim3(64, BB), 512, 0, stream>>>(XTB, GTB, S);
    k_topk<<<BB, 256, 0, stream>>>(S, wts, idx);
    k_combine<<<dim3(LL, BB), 128, 0, stream>>>(XB, wts, idx, XC);
    k_gemm3<<<dim3((BB * LL) / 128, DD / 128), 256, 0, stream>>>(XC, BM, bv, out);
}